// Round 1
// baseline (349.768 us; speedup 1.0000x reference)
//
#include <hip/hip_runtime.h>
#include <hip/hip_bf16.h>
#include <stdint.h>

#define N_TOK 32768
#define D_IN  1024
#define U_OUT 1024

typedef __attribute__((ext_vector_type(8))) short short8;
typedef __attribute__((ext_vector_type(4))) float f32x4;

__device__ __forceinline__ void async_copy16(const void* g, void* l) {
  __builtin_amdgcn_global_load_lds(
      (const __attribute__((address_space(1))) void*)g,
      (__attribute__((address_space(3))) void*)l,
      16, 0, 0);
}

// ---------------------------------------------------------------------------
// Kernel 1: per-row sign quantization (bf16 ±1) + beta = mean(|x|) per row.
// One 256-thread block per row; each thread handles 4 floats (float4 load).
// ---------------------------------------------------------------------------
__global__ __launch_bounds__(256) void quant_kernel(
    const float* __restrict__ x,
    unsigned short* __restrict__ xq,   // bf16 bit patterns [N_TOK][D_IN]
    float* __restrict__ beta) {
  const int row = blockIdx.x;
  const int tid = threadIdx.x;
  const float4 v = ((const float4*)(x + (size_t)row * D_IN))[tid];

  ushort4 s;
  s.x = (v.x >= 0.f) ? 0x3F80u : 0xBF80u;   // bf16 +1 / -1
  s.y = (v.y >= 0.f) ? 0x3F80u : 0xBF80u;
  s.z = (v.z >= 0.f) ? 0x3F80u : 0xBF80u;
  s.w = (v.w >= 0.f) ? 0x3F80u : 0xBF80u;
  ((ushort4*)(xq + (size_t)row * D_IN))[tid] = s;

  float asum = fabsf(v.x) + fabsf(v.y) + fabsf(v.z) + fabsf(v.w);
  #pragma unroll
  for (int off = 32; off > 0; off >>= 1)
    asum += __shfl_down(asum, off, 64);

  __shared__ float part[4];
  if ((tid & 63) == 0) part[tid >> 6] = asum;
  __syncthreads();
  if (tid == 0)
    beta[row] = (part[0] + part[1] + part[2] + part[3]) * (1.0f / (float)D_IN);
}

// ---------------------------------------------------------------------------
// Kernel 2: Wt[u][d] = sum_e a_e[u]*sign(k_e[d][u])  (bf16, transposed layout
// so the GEMM B-operand is contiguous in K). 64x64 tiles via LDS transpose.
// ---------------------------------------------------------------------------
__global__ __launch_bounds__(256) void wt_kernel(
    const float* __restrict__ k0, const float* __restrict__ k1,
    const float* __restrict__ k2,
    const float* __restrict__ a0, const float* __restrict__ a1,
    const float* __restrict__ a2,
    unsigned short* __restrict__ wt) {   // bf16 [U_OUT][D_IN]
  __shared__ float tile[64][65];         // +1 pad breaks bank conflicts
  const int d0 = blockIdx.x * 64;
  const int u0 = blockIdx.y * 64;
  const int tid = threadIdx.x;

  const int u_local = tid >> 2;          // 0..63
  const int dbase   = (tid & 3) * 16;    // 0,16,32,48
  float acc[16];
  #pragma unroll
  for (int j = 0; j < 16; j++) acc[j] = 0.f;

  const float* ks[3] = {k0, k1, k2};
  const float* as[3] = {a0, a1, a2};

  for (int e = 0; e < 3; e++) {
    __syncthreads();
    const int col   = tid & 63;
    const int rbase = tid >> 6;          // 0..3
    #pragma unroll
    for (int i = 0; i < 16; i++) {
      const int r = rbase + i * 4;
      tile[r][col] = ks[e][(size_t)(d0 + r) * U_OUT + (u0 + col)];
    }
    __syncthreads();
    const float a = as[e][u0 + u_local];
    #pragma unroll
    for (int j = 0; j < 16; j++) {
      const float kv = tile[dbase + j][u_local];
      acc[j] += (kv >= 0.f) ? a : -a;
    }
  }

  const size_t base = (size_t)(u0 + u_local) * D_IN + d0 + dbase;
  #pragma unroll
  for (int j = 0; j < 16; j++) {
    __hip_bfloat16 h = __float2bfloat16(acc[j]);
    wt[base + j] = *(unsigned short*)&h;
  }
}

// ---------------------------------------------------------------------------
// Kernel 3: C[n,u] = beta[n] * (Xq[n,:] @ W[:,u]), m97-style bf16 MFMA GEMM.
// A = Xq [M,K] row-major bf16; Bt = Wt [N,K] row-major bf16 (B transposed).
// 128x128 tile, BK=32, 4 waves in 2x2, each wave 4x4 mfma_f32_16x16x32_bf16.
// ---------------------------------------------------------------------------
#define BM 128
#define BN 128
#define BK 32

__global__ __launch_bounds__(256, 2) void gemm_kernel(
    const unsigned short* __restrict__ A,   // [M,K] bf16 bits
    const unsigned short* __restrict__ Bt,  // [N,K] bf16 bits
    const float* __restrict__ beta,
    float* __restrict__ C) {
  const int M = N_TOK, N = U_OUT, K = D_IN;
  __shared__ unsigned short As[BM * BK];    // 8 KB, lane-ordered (no padding:
  __shared__ unsigned short Bs[BN * BK];    // global_load_lds requires it)

  const int bid = blockIdx.x;
  const int nt  = bid & 7;                  // 8 n-tiles (1024/128)
  const int mt  = bid >> 3;                 // 256 m-tiles
  const int m0  = mt * BM;
  const int n0  = nt * BN;
  (void)M;

  const int tid  = threadIdx.x;
  const int wave = tid >> 6;
  const int lane = tid & 63;
  const int wr   = wave >> 1;               // 0,1  (m half)
  const int wc   = wave & 1;                // 0,1  (n half)
  const int lrow = lane & 15;
  const int quad = lane >> 4;

  f32x4 acc[4][4] = {};

  for (int kk = 0; kk < K; kk += BK) {
    // ---- stage A/B tiles: 512 x 16B segments each tile, 2 per thread ----
    #pragma unroll
    for (int half = 0; half < 2; half++) {
      const int s   = tid + half * 256;     // 0..511
      const int row = s >> 2;               // 0..127
      const int c   = (s & 3) * 8;          // bf16 elements within row
      async_copy16(A  + (size_t)(m0 + row) * K + kk + c, As + (size_t)s * 8);
      async_copy16(Bt + (size_t)(n0 + row) * K + kk + c, Bs + (size_t)s * 8);
    }
    __syncthreads();   // compiler drains vmcnt before s_barrier

    short8 af[4], bf[4];
    #pragma unroll
    for (int i = 0; i < 4; i++) {
      af[i] = *(const short8*)(As + (wr * 64 + i * 16 + lrow) * BK + quad * 8);
      bf[i] = *(const short8*)(Bs + (wc * 64 + i * 16 + lrow) * BK + quad * 8);
    }
    #pragma unroll
    for (int mi = 0; mi < 4; mi++)
      #pragma unroll
      for (int ni = 0; ni < 4; ni++)
        acc[mi][ni] = __builtin_amdgcn_mfma_f32_16x16x32_bf16(
            af[mi], bf[ni], acc[mi][ni], 0, 0, 0);
    __syncthreads();
  }

  // ---- epilogue: scale by beta[row], store f32 ----
  // C/D layout: col = lane&15, row = quad*4 + reg   [measured m89/m91]
  #pragma unroll
  for (int mi = 0; mi < 4; mi++) {
    #pragma unroll
    for (int r = 0; r < 4; r++) {
      const int row = m0 + wr * 64 + mi * 16 + quad * 4 + r;
      const float b = beta[row];
      #pragma unroll
      for (int ni = 0; ni < 4; ni++) {
        const int col = n0 + wc * 64 + ni * 16 + lrow;
        C[(size_t)row * N + col] = acc[mi][ni][r] * b;
      }
    }
  }
}

// ---------------------------------------------------------------------------
extern "C" void kernel_launch(void* const* d_in, const int* in_sizes, int n_in,
                              void* d_out, int out_size, void* d_ws, size_t ws_size,
                              hipStream_t stream) {
  const float* x  = (const float*)d_in[0];
  const float* k0 = (const float*)d_in[1];
  const float* k1 = (const float*)d_in[2];
  const float* k2 = (const float*)d_in[3];
  const float* a0 = (const float*)d_in[4];
  const float* a1 = (const float*)d_in[5];
  const float* a2 = (const float*)d_in[6];
  float* out = (float*)d_out;

  char* ws = (char*)d_ws;
  unsigned short* xq   = (unsigned short*)ws;                          // 64 MiB
  unsigned short* wt   = (unsigned short*)(ws + (size_t)N_TOK * D_IN * 2);  // 2 MiB
  float*          beta = (float*)(ws + (size_t)N_TOK * D_IN * 2
                                     + (size_t)U_OUT * D_IN * 2);      // 128 KiB

  quant_kernel<<<N_TOK, 256, 0, stream>>>(x, xq, beta);
  wt_kernel<<<dim3(D_IN / 64, U_OUT / 64), 256, 0, stream>>>(
      k0, k1, k2, a0, a1, a2, wt);
  gemm_kernel<<<(N_TOK / BM) * (U_OUT / BN), 256, 0, stream>>>(xq, wt, beta, out);
}